// Round 9
// baseline (1151.473 us; speedup 1.0000x reference)
//
#include <hip/hip_runtime.h>
#include <hip/hip_bf16.h>

#define N_NODES 50000
#define N_EDGES 800000
#define N_REL   3
#define F_IN    256
#define CH      128
#define BATCH   4096
#define DT      0.25f
#define NRANGE  8
#define RSPAN   6250   // N_NODES / NRANGE exactly

typedef __bf16 bf16x8 __attribute__((ext_vector_type(8)));
typedef float f32x4 __attribute__((ext_vector_type(4)));

__device__ __forceinline__ ushort f2bf(float f) {
  unsigned u = __float_as_uint(f);
  return (ushort)((u + 0x7FFFu + ((u >> 16) & 1u)) >> 16);  // RNE
}
__device__ __forceinline__ float bf2f(ushort h) {
  return __uint_as_float((unsigned)h << 16);
}

// flag[0] = inputs are int64 (vs int32); flag[1] = some node has in-degree 0
__global__ void k_detect(const int* __restrict__ ei, int* __restrict__ flag) {
  int lane = threadIdx.x;
  int v = ei[2 * lane + 1];
  unsigned long long m = __ballot(v != 0);
  if (lane == 0) flag[0] = (m == 0ull) ? 1 : 0;
}

// XCD-range-pinned in-degree histogram.
__global__ void k_hist3x(const int* __restrict__ ei, const int* __restrict__ flag,
                         int* __restrict__ deg3) {
  int b = blockIdx.x;
  int q = b & (NRANGE - 1), chunk = b >> 3;
  int e = chunk * 256 + threadIdx.x;
  int r = blockIdx.y;
  if (e >= N_EDGES) return;
  long ci = (long)r * 2 * N_EDGES + N_EDGES + e;
  int d = flag[0] ? ei[2 * ci] : ei[ci];
  if (d / RSPAN == q) atomicAdd(&deg3[r * N_NODES + d], 1);
}

__global__ void k_dinv3(const int* __restrict__ deg3, float* __restrict__ dinv3,
                        int* __restrict__ flag) {
  int i = blockIdx.x * blockDim.x + threadIdx.x;
  if (i >= 3 * N_NODES) return;
  int d = deg3[i];
  if (d > 0) {
    dinv3[i] = rsqrtf((float)d);
  } else {
    dinv3[i] = 0.0f;
    atomicOr(&flag[1], 1);
  }
}

__global__ void k_scan3(const int* __restrict__ deg3, int* __restrict__ off3) {
  __shared__ int sm[1024];
  const int* deg = deg3 + blockIdx.x * N_NODES;
  int* off = off3 + blockIdx.x * (N_NODES + 1);
  int tid = threadIdx.x;
  const int PER = (N_NODES + 1023) / 1024;
  int base = tid * PER;
  int s = 0;
  for (int i = 0; i < PER; ++i) { int idx = base + i; if (idx < N_NODES) s += deg[idx]; }
  sm[tid] = s;
  __syncthreads();
  for (int d = 1; d < 1024; d <<= 1) {
    int v = 0;
    if (tid >= d) v = sm[tid - d];
    __syncthreads();
    sm[tid] += v;
    __syncthreads();
  }
  int run = sm[tid] - s;
  for (int i = 0; i < PER; ++i) {
    int idx = base + i;
    if (idx < N_NODES) { off[idx] = run; run += deg[idx]; }
  }
  if (tid == 1023) off[N_NODES] = run;
}

// XCD-range-pinned CSR fill. Fast: 4B src. Slow: int2 {src, w}.
__global__ void k_fill3x(const int* __restrict__ ei, const int* __restrict__ flag,
                         const int* __restrict__ off3, int* __restrict__ cur3,
                         const float* __restrict__ dinv3, void* __restrict__ csrv) {
  int b = blockIdx.x;
  int q = b & (NRANGE - 1), chunk = b >> 3;
  int e = chunk * 256 + threadIdx.x;
  int r = blockIdx.y;
  if (e >= N_EDGES) return;
  int i64 = flag[0], iso = flag[1];
  long ri = (long)r * 2 * N_EDGES + e;
  long ci = ri + N_EDGES;
  int d = i64 ? ei[2 * ci] : ei[ci];
  if (d / RSPAN != q) return;
  int s = i64 ? ei[2 * ri] : ei[ri];
  int pos = atomicAdd(&cur3[r * N_NODES + d], 1);
  int slot = off3[r * (N_NODES + 1) + d] + pos;
  if (iso) {
    const float* dinv = dinv3 + r * N_NODES;
    ((int2*)csrv)[(size_t)r * N_EDGES + slot] =
        make_int2(s, __float_as_int(dinv[s] * dinv[d]));
  } else {
    ((int*)csrv)[(size_t)r * N_EDGES + slot] = s;
  }
}

__global__ __launch_bounds__(256) void k_phi_mfma(
    const float* __restrict__ X, const float* __restrict__ W0,
    const float* __restrict__ b0, const float* __restrict__ W1,
    const float* __restrict__ b1, const float* __restrict__ dinv,
    const int* __restrict__ flag, float* __restrict__ P0,
    float* __restrict__ P1) {
  __shared__ ushort Ah[128 * 32], Al[128 * 32], Bh[128 * 32], Bl[128 * 32];
  const int tid = threadIdx.x;
  const int m0 = blockIdx.x * 128;
  const float* W = blockIdx.y ? W1 : W0;
  const float* bias = blockIdx.y ? b1 : b0;
  float* P = blockIdx.y ? P1 : P0;
  const int wid = tid >> 6, lane = tid & 63;
  const int wr = wid >> 1, wc = wid & 1;
  const int lr = lane & 15, k8 = lane >> 4;
  const int rt = tid >> 1, kb = (tid & 1) * 16;
  const bool mok = (m0 + rt) < N_NODES;
  const float* Xrow = X + (size_t)(m0 + rt) * F_IN;
  const float* Wrow = W + (size_t)rt * F_IN;
  f32x4 acc[4][4] = {};
  for (int k0 = 0; k0 < F_IN; k0 += 32) {
    float4 xa[4], wb[4];
#pragma unroll
    for (int j = 0; j < 4; ++j) {
      xa[j] = mok ? *(const float4*)(Xrow + k0 + kb + 4 * j)
                  : make_float4(0.f, 0.f, 0.f, 0.f);
      wb[j] = *(const float4*)(Wrow + k0 + kb + 4 * j);
    }
    if (k0) __syncthreads();
#pragma unroll
    for (int j = 0; j < 4; ++j) {
      int idx = rt * 32 + kb + 4 * j;
      ushort h0 = f2bf(xa[j].x), h1 = f2bf(xa[j].y), h2 = f2bf(xa[j].z), h3 = f2bf(xa[j].w);
      *(ushort4*)&Ah[idx] = make_ushort4(h0, h1, h2, h3);
      *(ushort4*)&Al[idx] =
          make_ushort4(f2bf(xa[j].x - bf2f(h0)), f2bf(xa[j].y - bf2f(h1)),
                       f2bf(xa[j].z - bf2f(h2)), f2bf(xa[j].w - bf2f(h3)));
      ushort g0 = f2bf(wb[j].x), g1 = f2bf(wb[j].y), g2 = f2bf(wb[j].z), g3 = f2bf(wb[j].w);
      *(ushort4*)&Bh[idx] = make_ushort4(g0, g1, g2, g3);
      *(ushort4*)&Bl[idx] =
          make_ushort4(f2bf(wb[j].x - bf2f(g0)), f2bf(wb[j].y - bf2f(g1)),
                       f2bf(wb[j].z - bf2f(g2)), f2bf(wb[j].w - bf2f(g3)));
    }
    __syncthreads();
    bf16x8 ah[4], al[4], bh[4], bl[4];
#pragma unroll
    for (int i = 0; i < 4; ++i) {
      int ao = (wr * 64 + i * 16 + lr) * 32 + k8 * 8;
      int bo = (wc * 64 + i * 16 + lr) * 32 + k8 * 8;
      ah[i] = *(const bf16x8*)&Ah[ao];
      al[i] = *(const bf16x8*)&Al[ao];
      bh[i] = *(const bf16x8*)&Bh[bo];
      bl[i] = *(const bf16x8*)&Bl[bo];
    }
#pragma unroll
    for (int i = 0; i < 4; ++i)
#pragma unroll
      for (int j = 0; j < 4; ++j) {
        acc[i][j] = __builtin_amdgcn_mfma_f32_16x16x32_bf16(ah[i], bh[j], acc[i][j], 0, 0, 0);
        acc[i][j] = __builtin_amdgcn_mfma_f32_16x16x32_bf16(ah[i], bl[j], acc[i][j], 0, 0, 0);
        acc[i][j] = __builtin_amdgcn_mfma_f32_16x16x32_bf16(al[i], bh[j], acc[i][j], 0, 0, 0);
      }
  }
  int iso = flag[1];
  float rsc[4][4];
#pragma unroll
  for (int i = 0; i < 4; ++i)
#pragma unroll
    for (int q = 0; q < 4; ++q) {
      int m = m0 + wr * 64 + i * 16 + k8 * 4 + q;
      rsc[i][q] = (m < N_NODES && !iso) ? dinv[m] : 1.0f;
    }
#pragma unroll
  for (int j = 0; j < 4; ++j) {
    int ch = wc * 64 + j * 16 + lr;
    float bv = bias[ch];
#pragma unroll
    for (int i = 0; i < 4; ++i) {
      int mbase = m0 + wr * 64 + i * 16 + k8 * 4;
#pragma unroll
      for (int q = 0; q < 4; ++q) {
        int m = mbase + q;
        if (m < N_NODES) P[(size_t)m * CH + ch] = (acc[i][j][q] + bv) * rsc[i][q];
      }
    }
  }
}

// fp32 -> bf16 mirror (linear, vectorized 8-wide)
__global__ void k_mir(const float* __restrict__ src, ushort* __restrict__ dst,
                      long n8) {
  long i = (long)blockIdx.x * 256 + threadIdx.x;
  if (i >= n8) return;
  f32x4 a = *(const f32x4*)(src + i * 8);
  f32x4 b = *(const f32x4*)(src + i * 8 + 4);
  uint4 m;
  m.x = (unsigned)f2bf(a[0]) | ((unsigned)f2bf(a[1]) << 16);
  m.y = (unsigned)f2bf(a[2]) | ((unsigned)f2bf(a[3]) << 16);
  m.z = (unsigned)f2bf(b[0]) | ((unsigned)f2bf(b[1]) << 16);
  m.w = (unsigned)f2bf(b[2]) | ((unsigned)f2bf(b[3]) << 16);
  *(uint4*)(dst + i * 8) = m;
}

__device__ __forceinline__ void bf8_fma(uint4 v, float w, f32x4& a0, f32x4& a1) {
  a0[0] = fmaf(w, __uint_as_float(v.x << 16), a0[0]);
  a0[1] = fmaf(w, __uint_as_float(v.x & 0xffff0000u), a0[1]);
  a0[2] = fmaf(w, __uint_as_float(v.y << 16), a0[2]);
  a0[3] = fmaf(w, __uint_as_float(v.y & 0xffff0000u), a0[3]);
  a1[0] = fmaf(w, __uint_as_float(v.z << 16), a1[0]);
  a1[1] = fmaf(w, __uint_as_float(v.z & 0xffff0000u), a1[1]);
  a1[2] = fmaf(w, __uint_as_float(v.w << 16), a1[2]);
  a1[3] = fmaf(w, __uint_as_float(v.w & 0xffff0000u), a1[3]);
}

// Mirror-gather prop: gathers bf16 mirror (half payload), keeps the exact
// recurrence (2*xc - xp) in fp32. Streams (sv/ov/out-fp32) are nontemporal so
// L2 retains mirror lines. Lane layout: 4 edge-groups x 16 lanes; lane l of a
// group loads one 16B row-slice (ch 8l..8l+7) per edge; group 0 writes.
__global__ __launch_bounds__(256, 8) void k_prop_m(
    const float* __restrict__ xcb, const ushort* __restrict__ mirb,
    const float* __restrict__ otherb, float* __restrict__ outb,
    ushort* __restrict__ omirb, const int* __restrict__ off3,
    const void* __restrict__ csrv, const int* __restrict__ flag,
    size_t slab, float wscale, float aself, float beta) {
  int node = blockIdx.x * 4 + (threadIdx.x >> 6);
  if (node >= N_NODES) return;
  int rel = blockIdx.y;
  const float*  xc    = xcb   + (size_t)rel * slab;
  const ushort* mir   = mirb  + (size_t)rel * slab;
  const float*  other = otherb+ (size_t)rel * slab;
  float*        out   = outb  + (size_t)rel * slab;
  ushort*       omir  = omirb + (size_t)rel * slab;
  const int* off = off3 + rel * (N_NODES + 1);
  int iso = flag[1];
  int lane = threadIdx.x & 63;
  int g = lane >> 4, l = lane & 15;
  int e0 = off[node], e1 = off[node + 1];
  size_t base = (size_t)node * CH;
  int co = l * 8;
  f32x4 sv0 = {}, sv1 = {}, ov0 = {}, ov1 = {};
  if (g == 0) {
    sv0 = __builtin_nontemporal_load((const f32x4*)(xc + base + co));
    sv1 = __builtin_nontemporal_load((const f32x4*)(xc + base + co + 4));
    ov0 = __builtin_nontemporal_load((const f32x4*)(other + base + co));
    ov1 = __builtin_nontemporal_load((const f32x4*)(other + base + co + 4));
  }
  f32x4 a0 = {}, a1 = {};
  if (!iso) {
    const int* csr = (const int*)csrv + (size_t)rel * N_EDGES;
    for (int e = e0; e < e1; e += 16) {
      int lim = e1 - 1;
      int src[4]; float wgt[4];
#pragma unroll
      for (int u = 0; u < 4; ++u) {
        int ee = e + 4 * u + g;
        src[u] = csr[min(ee, lim)];
        wgt[u] = (ee <= lim) ? 1.f : 0.f;
      }
      uint4 v[4];
#pragma unroll
      for (int u = 0; u < 4; ++u)
        v[u] = *(const uint4*)(mir + (size_t)src[u] * CH + co);
#pragma unroll
      for (int u = 0; u < 4; ++u) bf8_fma(v[u], wgt[u], a0, a1);
    }
  } else {
    const int2* csr = (const int2*)csrv + (size_t)rel * N_EDGES;
    for (int e = e0; e < e1; e += 16) {
      int lim = e1 - 1;
      int2 pm[4]; float wgt[4];
#pragma unroll
      for (int u = 0; u < 4; ++u) {
        int ee = e + 4 * u + g;
        pm[u] = csr[min(ee, lim)];
        wgt[u] = (ee <= lim) ? __int_as_float(pm[u].y) : 0.f;
      }
      uint4 v[4];
#pragma unroll
      for (int u = 0; u < 4; ++u)
        v[u] = *(const uint4*)(mir + (size_t)pm[u].x * CH + co);
#pragma unroll
      for (int u = 0; u < 4; ++u) bf8_fma(v[u], wgt[u], a0, a1);
    }
  }
#pragma unroll
  for (int m = 16; m < 64; m <<= 1) {
#pragma unroll
    for (int i = 0; i < 4; ++i) {
      a0[i] += __shfl_xor(a0[i], m);
      a1[i] += __shfl_xor(a1[i], m);
    }
  }
  if (g == 0) {
    float ws2 = iso ? wscale : ((e1 > e0) ? wscale / (float)(e1 - e0) : 0.f);
    f32x4 o0, o1;
#pragma unroll
    for (int i = 0; i < 4; ++i) {
      o0[i] = ws2 * a0[i] + aself * sv0[i] + beta * ov0[i];
      o1[i] = ws2 * a1[i] + aself * sv1[i] + beta * ov1[i];
    }
    __builtin_nontemporal_store(o0, (f32x4*)(out + base + co));
    __builtin_nontemporal_store(o1, (f32x4*)(out + base + co + 4));
    uint4 m;
    m.x = (unsigned)f2bf(o0[0]) | ((unsigned)f2bf(o0[1]) << 16);
    m.y = (unsigned)f2bf(o0[2]) | ((unsigned)f2bf(o0[3]) << 16);
    m.z = (unsigned)f2bf(o1[0]) | ((unsigned)f2bf(o1[1]) << 16);
    m.w = (unsigned)f2bf(o1[2]) | ((unsigned)f2bf(o1[3]) << 16);
    *(uint4*)(omir + base + co) = m;
  }
}

// Round-8 fp32-gather body (fallback tiers + gprop).
__device__ __forceinline__ void prop_accum(
    const float* __restrict__ xc, const void* __restrict__ csrv, int r, int iso,
    int e0, int e1, int g, int l, float4& acc0, float4& acc1) {
  if (!iso) {
    const int* csr = (const int*)csrv + (size_t)r * N_EDGES;
    for (int e = e0; e < e1; e += 16) {
      int lim = e1 - 1;
      int src[4]; float wgt[4];
#pragma unroll
      for (int u = 0; u < 4; ++u) {
        int ee = e + 4 * u + g;
        src[u] = csr[min(ee, lim)];
        wgt[u] = (ee <= lim) ? 1.f : 0.f;
      }
      float4 va[4], vb[4];
#pragma unroll
      for (int u = 0; u < 4; ++u) {
        const float4* rs = (const float4*)(xc + (size_t)src[u] * CH);
        va[u] = rs[l];
        vb[u] = rs[l + 16];
      }
#pragma unroll
      for (int u = 0; u < 4; ++u) {
        float w0 = wgt[u];
        acc0.x = fmaf(w0, va[u].x, acc0.x); acc0.y = fmaf(w0, va[u].y, acc0.y);
        acc0.z = fmaf(w0, va[u].z, acc0.z); acc0.w = fmaf(w0, va[u].w, acc0.w);
        acc1.x = fmaf(w0, vb[u].x, acc1.x); acc1.y = fmaf(w0, vb[u].y, acc1.y);
        acc1.z = fmaf(w0, vb[u].z, acc1.z); acc1.w = fmaf(w0, vb[u].w, acc1.w);
      }
    }
  } else {
    const int2* csr = (const int2*)csrv + (size_t)r * N_EDGES;
    for (int e = e0; e < e1; e += 16) {
      int lim = e1 - 1;
      int2 pm[4]; float wgt[4];
#pragma unroll
      for (int u = 0; u < 4; ++u) {
        int ee = e + 4 * u + g;
        pm[u] = csr[min(ee, lim)];
        wgt[u] = (ee <= lim) ? __int_as_float(pm[u].y) : 0.f;
      }
      float4 va[4], vb[4];
#pragma unroll
      for (int u = 0; u < 4; ++u) {
        const float4* rs = (const float4*)(xc + (size_t)pm[u].x * CH);
        va[u] = rs[l];
        vb[u] = rs[l + 16];
      }
#pragma unroll
      for (int u = 0; u < 4; ++u) {
        float w0 = wgt[u];
        acc0.x = fmaf(w0, va[u].x, acc0.x); acc0.y = fmaf(w0, va[u].y, acc0.y);
        acc0.z = fmaf(w0, va[u].z, acc0.z); acc0.w = fmaf(w0, va[u].w, acc0.w);
        acc1.x = fmaf(w0, vb[u].x, acc1.x); acc1.y = fmaf(w0, vb[u].y, acc1.y);
        acc1.z = fmaf(w0, vb[u].z, acc1.z); acc1.w = fmaf(w0, vb[u].w, acc1.w);
      }
    }
  }
}

__global__ __launch_bounds__(256, 8) void k_prop(
    const float* __restrict__ xcb, const float* __restrict__ otherb,
    float* __restrict__ outb, const int* __restrict__ off3,
    const void* __restrict__ csrv, const int* __restrict__ flag, int rel0,
    size_t slab, float wscale, float aself, float beta) {
  int node = blockIdx.x * 4 + (threadIdx.x >> 6);
  if (node >= N_NODES) return;
  int rel = rel0 + blockIdx.y;
  const float* xc = xcb + (size_t)blockIdx.y * slab;
  const float* other = otherb + (size_t)blockIdx.y * slab;
  float* out = outb + (size_t)blockIdx.y * slab;
  const int* off = off3 + rel * (N_NODES + 1);
  int iso = flag[1];
  int lane = threadIdx.x & 63;
  int g = lane >> 4, l = lane & 15;
  int e0 = off[node], e1 = off[node + 1];
  size_t base = (size_t)node * CH;
  int go = (g & 1) * 64;
  float4 sv = *(const float4*)(xc + base + go + 4 * l);
  float4 ov = *(const float4*)(other + base + go + 4 * l);
  float4 acc0 = make_float4(0.f, 0.f, 0.f, 0.f);
  float4 acc1 = make_float4(0.f, 0.f, 0.f, 0.f);
  prop_accum(xc, csrv, rel, iso, e0, e1, g, l, acc0, acc1);
#pragma unroll
  for (int m = 16; m < 64; m <<= 1) {
    acc0.x += __shfl_xor(acc0.x, m); acc0.y += __shfl_xor(acc0.y, m);
    acc0.z += __shfl_xor(acc0.z, m); acc0.w += __shfl_xor(acc0.w, m);
    acc1.x += __shfl_xor(acc1.x, m); acc1.y += __shfl_xor(acc1.y, m);
    acc1.z += __shfl_xor(acc1.z, m); acc1.w += __shfl_xor(acc1.w, m);
  }
  float ws2 = iso ? wscale : ((e1 > e0) ? wscale / (float)(e1 - e0) : 0.f);
  if (g == 0) {
    float4 o;
    o.x = ws2 * acc0.x + aself * sv.x + beta * ov.x;
    o.y = ws2 * acc0.y + aself * sv.y + beta * ov.y;
    o.z = ws2 * acc0.z + aself * sv.z + beta * ov.z;
    o.w = ws2 * acc0.w + aself * sv.w + beta * ov.w;
    *(float4*)(out + base + 4 * l) = o;
  } else if (g == 1) {
    float4 o;
    o.x = ws2 * acc1.x + aself * sv.x + beta * ov.x;
    o.y = ws2 * acc1.y + aself * sv.y + beta * ov.y;
    o.z = ws2 * acc1.z + aself * sv.z + beta * ov.z;
    o.w = ws2 * acc1.w + aself * sv.w + beta * ov.w;
    *(float4*)(out + base + 64 + 4 * l) = o;
  }
}

// Fused final step + batch gather (+ sqrt(deg) rescale on fast path).
__global__ __launch_bounds__(256) void k_gprop(
    const float* __restrict__ y3b, const float* __restrict__ y2b,
    const int* __restrict__ off3, const void* __restrict__ csrv,
    const int* __restrict__ flag, const int* __restrict__ batch,
    float* __restrict__ out, int rel0, size_t slab,
    float wscale, float aself, float beta) {
  int b = blockIdx.x * 4 + (threadIdx.x >> 6);
  if (b >= BATCH) return;
  int rel = rel0 + blockIdx.y;
  const float* y3 = y3b + (size_t)blockIdx.y * slab;
  const float* y2 = y2b + (size_t)blockIdx.y * slab;
  const int* off = off3 + rel * (N_NODES + 1);
  int i64 = flag[0], iso = flag[1];
  int node = i64 ? batch[2 * b] : batch[b];
  int lane = threadIdx.x & 63;
  int g = lane >> 4, l = lane & 15;
  int e0 = off[node], e1 = off[node + 1];
  size_t base = (size_t)node * CH;
  int go = (g & 1) * 64;
  float4 sv = *(const float4*)(y3 + base + go + 4 * l);
  float4 ov = *(const float4*)(y2 + base + go + 4 * l);
  float4 acc0 = make_float4(0.f, 0.f, 0.f, 0.f);
  float4 acc1 = make_float4(0.f, 0.f, 0.f, 0.f);
  prop_accum(y3, csrv, rel, iso, e0, e1, g, l, acc0, acc1);
#pragma unroll
  for (int m = 16; m < 64; m <<= 1) {
    acc0.x += __shfl_xor(acc0.x, m); acc0.y += __shfl_xor(acc0.y, m);
    acc0.z += __shfl_xor(acc0.z, m); acc0.w += __shfl_xor(acc0.w, m);
    acc1.x += __shfl_xor(acc1.x, m); acc1.y += __shfl_xor(acc1.y, m);
    acc1.z += __shfl_xor(acc1.z, m); acc1.w += __shfl_xor(acc1.w, m);
  }
  int deg = e1 - e0;
  float ws2 = iso ? wscale : ((deg > 0) ? wscale / (float)deg : 0.f);
  float osc = iso ? 1.0f : sqrtf((float)deg);
  float* orow = out + (size_t)b * (N_REL * CH) + rel * CH;
  if (g == 0) {
    float4 o;
    o.x = osc * (ws2 * acc0.x + aself * sv.x + beta * ov.x);
    o.y = osc * (ws2 * acc0.y + aself * sv.y + beta * ov.y);
    o.z = osc * (ws2 * acc0.z + aself * sv.z + beta * ov.z);
    o.w = osc * (ws2 * acc0.w + aself * sv.w + beta * ov.w);
    *(float4*)(orow + 4 * l) = o;
  } else if (g == 1) {
    float4 o;
    o.x = osc * (ws2 * acc1.x + aself * sv.x + beta * ov.x);
    o.y = osc * (ws2 * acc1.y + aself * sv.y + beta * ov.y);
    o.z = osc * (ws2 * acc1.z + aself * sv.z + beta * ov.z);
    o.w = osc * (ws2 * acc1.w + aself * sv.w + beta * ov.w);
    *(float4*)(orow + 64 + 4 * l) = o;
  }
}

extern "C" void kernel_launch(void* const* d_in, const int* in_sizes, int n_in,
                              void* d_out, int out_size, void* d_ws, size_t ws_size,
                              hipStream_t stream) {
  const float* features   = (const float*)d_in[0];
  const int*   edge_index = (const int*)d_in[1];
  const int*   batch_nodes= (const int*)d_in[2];
  const float* lin0_w     = (const float*)d_in[3];
  const float* lin0_b     = (const float*)d_in[4];
  const float* lin1_w     = (const float*)d_in[5];
  const float* lin1_b     = (const float*)d_in[6];
  float* out = (float*)d_out;

  const size_t slabElems = (size_t)N_NODES * CH;

  char* w = (char*)d_ws;
  size_t o = 0;
  auto nxt = [&](size_t bytes) {
    char* p = w + o;
    o = (o + bytes + 255) & ~(size_t)255;
    return p;
  };
  int*   flag  = (int*)  nxt(256);
  int*   deg3  = (int*)  nxt((size_t)3 * N_NODES * 4);
  int*   cur3  = (int*)  nxt((size_t)3 * N_NODES * 4);
  float* dinv3 = (float*)nxt((size_t)3 * N_NODES * 4);
  int*   off3  = (int*)  nxt((size_t)3 * (N_NODES + 1) * 4);
  void*  csr   = (void*) nxt((size_t)3 * N_EDGES * 8);
  size_t avail = (ws_size > o) ? ws_size - o : 0;
  const bool fused = avail >= 2 * 3 * slabElems * 4 + 4096;
  const bool mirOk = avail >= 2 * 3 * slabElems * 4 + 2 * 3 * slabElems * 2 + 8192;
  const int nslab = fused ? 3 : 1;
  float*  A    = (float*) nxt((size_t)nslab * slabElems * 4);
  float*  B    = (float*) nxt((size_t)nslab * slabElems * 4);
  ushort* Amir = mirOk ? (ushort*)nxt((size_t)3 * slabElems * 2) : nullptr;
  ushort* Bmir = mirOk ? (ushort*)nxt((size_t)3 * slabElems * 2) : nullptr;

  hipMemsetAsync(flag, 0, 8, stream);
  hipMemsetAsync(deg3, 0, (size_t)3 * N_NODES * 4, stream);
  hipMemsetAsync(cur3, 0, (size_t)3 * N_NODES * 4, stream);
  k_detect<<<1, 64, 0, stream>>>(edge_index, flag);
  const int NCHUNK = (N_EDGES + 255) / 256;   // 3125
  k_hist3x<<<dim3(NCHUNK * NRANGE, 3), 256, 0, stream>>>(edge_index, flag, deg3);
  k_dinv3<<<(3 * N_NODES + 255) / 256, 256, 0, stream>>>(deg3, dinv3, flag);
  k_scan3<<<3, 1024, 0, stream>>>(deg3, off3);
  k_fill3x<<<dim3(NCHUNK * NRANGE, 3), 256, 0, stream>>>(edge_index, flag, off3,
                                                         cur3, dinv3, csr);

  const float h2 = DT * DT;
  if (fused) {
    for (int r = 0; r < N_REL; ++r) {
      k_phi_mfma<<<dim3((N_NODES + 127) / 128, 2), 256, 0, stream>>>(
          features, lin0_w + (size_t)r * CH * F_IN, lin0_b + (size_t)r * CH,
          lin1_w + (size_t)r * CH * F_IN, lin1_b + (size_t)r * CH,
          dinv3 + r * N_NODES, flag, A + (size_t)r * slabElems,
          B + (size_t)r * slabElems);
    }
    const long n8 = (long)3 * slabElems / 8;
    if (mirOk) {
      k_mir<<<(int)((n8 + 255) / 256), 256, 0, stream>>>(A, Amir, n8);
      // Y1 = dt*q1 + 0.5h^2*Sum(q0) + q0   : gather Amir -> B, Bmir
      k_prop_m<<<dim3((N_NODES + 3) / 4, 3), 256, 0, stream>>>(
          A, Amir, B, B, Bmir, off3, csr, flag, slabElems, 0.5f * h2, 1.0f, DT);
      // Y2 = h^2*Sum(Y1) + 2*Y1 - q0       : gather Bmir -> A, Amir
      k_prop_m<<<dim3((N_NODES + 3) / 4, 3), 256, 0, stream>>>(
          B, Bmir, A, A, Amir, off3, csr, flag, slabElems, h2, 2.0f, -1.0f);
      // Y3 = h^2*Sum(Y2) + 2*Y2 - Y1       : gather Amir -> B, Bmir
      k_prop_m<<<dim3((N_NODES + 3) / 4, 3), 256, 0, stream>>>(
          A, Amir, B, B, Bmir, off3, csr, flag, slabElems, h2, 2.0f, -1.0f);
    } else {
      k_prop<<<dim3((N_NODES + 3) / 4, 3), 256, 0, stream>>>(
          A, B, B, off3, csr, flag, 0, slabElems, 0.5f * h2, 1.0f, DT);
      k_prop<<<dim3((N_NODES + 3) / 4, 3), 256, 0, stream>>>(
          B, A, A, off3, csr, flag, 0, slabElems, h2, 2.0f, -1.0f);
      k_prop<<<dim3((N_NODES + 3) / 4, 3), 256, 0, stream>>>(
          A, B, B, off3, csr, flag, 0, slabElems, h2, 2.0f, -1.0f);
    }
    // Y4[batch] fused with gather -> out (fp32 gather of Y3 = B)
    k_gprop<<<dim3((BATCH + 3) / 4, 3), 256, 0, stream>>>(
        B, A, off3, csr, flag, batch_nodes, out, 0, slabElems, h2, 2.0f, -1.0f);
  } else {
    for (int r = 0; r < N_REL; ++r) {
      k_phi_mfma<<<dim3((N_NODES + 127) / 128, 2), 256, 0, stream>>>(
          features, lin0_w + (size_t)r * CH * F_IN, lin0_b + (size_t)r * CH,
          lin1_w + (size_t)r * CH * F_IN, lin1_b + (size_t)r * CH,
          dinv3 + r * N_NODES, flag, A, B);
      k_prop<<<dim3((N_NODES + 3) / 4, 1), 256, 0, stream>>>(
          A, B, B, off3, csr, flag, r, 0, 0.5f * h2, 1.0f, DT);
      k_prop<<<dim3((N_NODES + 3) / 4, 1), 256, 0, stream>>>(
          B, A, A, off3, csr, flag, r, 0, h2, 2.0f, -1.0f);
      k_prop<<<dim3((N_NODES + 3) / 4, 1), 256, 0, stream>>>(
          A, B, B, off3, csr, flag, r, 0, h2, 2.0f, -1.0f);
      k_gprop<<<dim3((BATCH + 3) / 4, 1), 256, 0, stream>>>(
          B, A, off3, csr, flag, batch_nodes, out, r, 0, h2, 2.0f, -1.0f);
    }
  }
}

// Round 10
// 1137.245 us; speedup vs baseline: 1.0125x; 1.0125x over previous
//
#include <hip/hip_runtime.h>
#include <hip/hip_bf16.h>

#define N_NODES 50000
#define N_EDGES 800000
#define N_REL   3
#define F_IN    256
#define CH      128
#define BATCH   4096
#define DT      0.25f
#define NRANGE  8
#define RSPAN   6250   // N_NODES / NRANGE exactly

typedef __bf16 bf16x8 __attribute__((ext_vector_type(8)));
typedef float f32x4 __attribute__((ext_vector_type(4)));

__device__ __forceinline__ ushort f2bf(float f) {
  unsigned u = __float_as_uint(f);
  return (ushort)((u + 0x7FFFu + ((u >> 16) & 1u)) >> 16);  // RNE
}
__device__ __forceinline__ float bf2f(ushort h) {
  return __uint_as_float((unsigned)h << 16);
}

// flag[0] = inputs are int64 (vs int32); flag[1] = some node has in-degree 0
__global__ void k_detect(const int* __restrict__ ei, int* __restrict__ flag) {
  int lane = threadIdx.x;
  int v = ei[2 * lane + 1];
  unsigned long long m = __ballot(v != 0);
  if (lane == 0) flag[0] = (m == 0ull) ? 1 : 0;
}

// XCD-range-pinned in-degree histogram.
__global__ void k_hist3x(const int* __restrict__ ei, const int* __restrict__ flag,
                         int* __restrict__ deg3) {
  int b = blockIdx.x;
  int q = b & (NRANGE - 1), chunk = b >> 3;
  int e = chunk * 256 + threadIdx.x;
  int r = blockIdx.y;
  if (e >= N_EDGES) return;
  long ci = (long)r * 2 * N_EDGES + N_EDGES + e;
  int d = flag[0] ? ei[2 * ci] : ei[ci];
  if (d / RSPAN == q) atomicAdd(&deg3[r * N_NODES + d], 1);
}

__global__ void k_dinv3(const int* __restrict__ deg3, float* __restrict__ dinv3,
                        int* __restrict__ flag) {
  int i = blockIdx.x * blockDim.x + threadIdx.x;
  if (i >= 3 * N_NODES) return;
  int d = deg3[i];
  if (d > 0) {
    dinv3[i] = rsqrtf((float)d);
  } else {
    dinv3[i] = 0.0f;
    atomicOr(&flag[1], 1);
  }
}

__global__ void k_scan3(const int* __restrict__ deg3, int* __restrict__ off3) {
  __shared__ int sm[1024];
  const int* deg = deg3 + blockIdx.x * N_NODES;
  int* off = off3 + blockIdx.x * (N_NODES + 1);
  int tid = threadIdx.x;
  const int PER = (N_NODES + 1023) / 1024;
  int base = tid * PER;
  int s = 0;
  for (int i = 0; i < PER; ++i) { int idx = base + i; if (idx < N_NODES) s += deg[idx]; }
  sm[tid] = s;
  __syncthreads();
  for (int d = 1; d < 1024; d <<= 1) {
    int v = 0;
    if (tid >= d) v = sm[tid - d];
    __syncthreads();
    sm[tid] += v;
    __syncthreads();
  }
  int run = sm[tid] - s;
  for (int i = 0; i < PER; ++i) {
    int idx = base + i;
    if (idx < N_NODES) { off[idx] = run; run += deg[idx]; }
  }
  if (tid == 1023) off[N_NODES] = run;
}

// XCD-range-pinned CSR fill. Fast: 4B src. Slow: int2 {src, w}.
__global__ void k_fill3x(const int* __restrict__ ei, const int* __restrict__ flag,
                         const int* __restrict__ off3, int* __restrict__ cur3,
                         const float* __restrict__ dinv3, void* __restrict__ csrv) {
  int b = blockIdx.x;
  int q = b & (NRANGE - 1), chunk = b >> 3;
  int e = chunk * 256 + threadIdx.x;
  int r = blockIdx.y;
  if (e >= N_EDGES) return;
  int i64 = flag[0], iso = flag[1];
  long ri = (long)r * 2 * N_EDGES + e;
  long ci = ri + N_EDGES;
  int d = i64 ? ei[2 * ci] : ei[ci];
  if (d / RSPAN != q) return;
  int s = i64 ? ei[2 * ri] : ei[ri];
  int pos = atomicAdd(&cur3[r * N_NODES + d], 1);
  int slot = off3[r * (N_NODES + 1) + d] + pos;
  if (iso) {
    const float* dinv = dinv3 + r * N_NODES;
    ((int2*)csrv)[(size_t)r * N_EDGES + slot] =
        make_int2(s, __float_as_int(dinv[s] * dinv[d]));
  } else {
    ((int*)csrv)[(size_t)r * N_EDGES + slot] = s;
  }
}

__global__ __launch_bounds__(256) void k_phi_mfma(
    const float* __restrict__ X, const float* __restrict__ W0,
    const float* __restrict__ b0, const float* __restrict__ W1,
    const float* __restrict__ b1, const float* __restrict__ dinv,
    const int* __restrict__ flag, float* __restrict__ P0,
    float* __restrict__ P1) {
  __shared__ ushort Ah[128 * 32], Al[128 * 32], Bh[128 * 32], Bl[128 * 32];
  const int tid = threadIdx.x;
  const int m0 = blockIdx.x * 128;
  const float* W = blockIdx.y ? W1 : W0;
  const float* bias = blockIdx.y ? b1 : b0;
  float* P = blockIdx.y ? P1 : P0;
  const int wid = tid >> 6, lane = tid & 63;
  const int wr = wid >> 1, wc = wid & 1;
  const int lr = lane & 15, k8 = lane >> 4;
  const int rt = tid >> 1, kb = (tid & 1) * 16;
  const bool mok = (m0 + rt) < N_NODES;
  const float* Xrow = X + (size_t)(m0 + rt) * F_IN;
  const float* Wrow = W + (size_t)rt * F_IN;
  f32x4 acc[4][4] = {};
  for (int k0 = 0; k0 < F_IN; k0 += 32) {
    float4 xa[4], wb[4];
#pragma unroll
    for (int j = 0; j < 4; ++j) {
      xa[j] = mok ? *(const float4*)(Xrow + k0 + kb + 4 * j)
                  : make_float4(0.f, 0.f, 0.f, 0.f);
      wb[j] = *(const float4*)(Wrow + k0 + kb + 4 * j);
    }
    if (k0) __syncthreads();
#pragma unroll
    for (int j = 0; j < 4; ++j) {
      int idx = rt * 32 + kb + 4 * j;
      ushort h0 = f2bf(xa[j].x), h1 = f2bf(xa[j].y), h2 = f2bf(xa[j].z), h3 = f2bf(xa[j].w);
      *(ushort4*)&Ah[idx] = make_ushort4(h0, h1, h2, h3);
      *(ushort4*)&Al[idx] =
          make_ushort4(f2bf(xa[j].x - bf2f(h0)), f2bf(xa[j].y - bf2f(h1)),
                       f2bf(xa[j].z - bf2f(h2)), f2bf(xa[j].w - bf2f(h3)));
      ushort g0 = f2bf(wb[j].x), g1 = f2bf(wb[j].y), g2 = f2bf(wb[j].z), g3 = f2bf(wb[j].w);
      *(ushort4*)&Bh[idx] = make_ushort4(g0, g1, g2, g3);
      *(ushort4*)&Bl[idx] =
          make_ushort4(f2bf(wb[j].x - bf2f(g0)), f2bf(wb[j].y - bf2f(g1)),
                       f2bf(wb[j].z - bf2f(g2)), f2bf(wb[j].w - bf2f(g3)));
    }
    __syncthreads();
    bf16x8 ah[4], al[4], bh[4], bl[4];
#pragma unroll
    for (int i = 0; i < 4; ++i) {
      int ao = (wr * 64 + i * 16 + lr) * 32 + k8 * 8;
      int bo = (wc * 64 + i * 16 + lr) * 32 + k8 * 8;
      ah[i] = *(const bf16x8*)&Ah[ao];
      al[i] = *(const bf16x8*)&Al[ao];
      bh[i] = *(const bf16x8*)&Bh[bo];
      bl[i] = *(const bf16x8*)&Bl[bo];
    }
#pragma unroll
    for (int i = 0; i < 4; ++i)
#pragma unroll
      for (int j = 0; j < 4; ++j) {
        acc[i][j] = __builtin_amdgcn_mfma_f32_16x16x32_bf16(ah[i], bh[j], acc[i][j], 0, 0, 0);
        acc[i][j] = __builtin_amdgcn_mfma_f32_16x16x32_bf16(ah[i], bl[j], acc[i][j], 0, 0, 0);
        acc[i][j] = __builtin_amdgcn_mfma_f32_16x16x32_bf16(al[i], bh[j], acc[i][j], 0, 0, 0);
      }
  }
  int iso = flag[1];
  float rsc[4][4];
#pragma unroll
  for (int i = 0; i < 4; ++i)
#pragma unroll
    for (int q = 0; q < 4; ++q) {
      int m = m0 + wr * 64 + i * 16 + k8 * 4 + q;
      rsc[i][q] = (m < N_NODES && !iso) ? dinv[m] : 1.0f;
    }
#pragma unroll
  for (int j = 0; j < 4; ++j) {
    int ch = wc * 64 + j * 16 + lr;
    float bv = bias[ch];
#pragma unroll
    for (int i = 0; i < 4; ++i) {
      int mbase = m0 + wr * 64 + i * 16 + k8 * 4;
#pragma unroll
      for (int q = 0; q < 4; ++q) {
        int m = mbase + q;
        if (m < N_NODES) P[(size_t)m * CH + ch] = (acc[i][j][q] + bv) * rsc[i][q];
      }
    }
  }
}

// fp32 -> bf16 mirror (linear, vectorized 8-wide)
__global__ void k_mir(const float* __restrict__ src, ushort* __restrict__ dst,
                      long n8) {
  long i = (long)blockIdx.x * 256 + threadIdx.x;
  if (i >= n8) return;
  f32x4 a = *(const f32x4*)(src + i * 8);
  f32x4 b = *(const f32x4*)(src + i * 8 + 4);
  uint4 m;
  m.x = (unsigned)f2bf(a[0]) | ((unsigned)f2bf(a[1]) << 16);
  m.y = (unsigned)f2bf(a[2]) | ((unsigned)f2bf(a[3]) << 16);
  m.z = (unsigned)f2bf(b[0]) | ((unsigned)f2bf(b[1]) << 16);
  m.w = (unsigned)f2bf(b[2]) | ((unsigned)f2bf(b[3]) << 16);
  *(uint4*)(dst + i * 8) = m;
}

__device__ __forceinline__ void bf8_fma(uint4 v, float w, f32x4& a0, f32x4& a1) {
  a0[0] = fmaf(w, __uint_as_float(v.x << 16), a0[0]);
  a0[1] = fmaf(w, __uint_as_float(v.x & 0xffff0000u), a0[1]);
  a0[2] = fmaf(w, __uint_as_float(v.y << 16), a0[2]);
  a0[3] = fmaf(w, __uint_as_float(v.y & 0xffff0000u), a0[3]);
  a1[0] = fmaf(w, __uint_as_float(v.z << 16), a1[0]);
  a1[1] = fmaf(w, __uint_as_float(v.z & 0xffff0000u), a1[1]);
  a1[2] = fmaf(w, __uint_as_float(v.w << 16), a1[2]);
  a1[3] = fmaf(w, __uint_as_float(v.w & 0xffff0000u), a1[3]);
}

// Mirror-gather prop: gathers bf16 mirror (half payload), exact fp32
// recurrence. nt LOADS on the sv/ov streams (no reuse -> don't pollute L2);
// PLAIN cached stores (round-9 nt stores caused 4x HBM write amplification).
__global__ __launch_bounds__(256, 8) void k_prop_m(
    const float* __restrict__ xcb, const ushort* __restrict__ mirb,
    const float* __restrict__ otherb, float* __restrict__ outb,
    ushort* __restrict__ omirb, const int* __restrict__ off3,
    const void* __restrict__ csrv, const int* __restrict__ flag,
    size_t slab, float wscale, float aself, float beta) {
  int node = blockIdx.x * 4 + (threadIdx.x >> 6);
  if (node >= N_NODES) return;
  int rel = blockIdx.y;
  const float*  xc    = xcb   + (size_t)rel * slab;
  const ushort* mir   = mirb  + (size_t)rel * slab;
  const float*  other = otherb+ (size_t)rel * slab;
  float*        out   = outb  + (size_t)rel * slab;
  ushort*       omir  = omirb + (size_t)rel * slab;
  const int* off = off3 + rel * (N_NODES + 1);
  int iso = flag[1];
  int lane = threadIdx.x & 63;
  int g = lane >> 4, l = lane & 15;
  int e0 = off[node], e1 = off[node + 1];
  size_t base = (size_t)node * CH;
  int co = l * 8;
  f32x4 sv0 = {}, sv1 = {}, ov0 = {}, ov1 = {};
  if (g == 0) {
    sv0 = __builtin_nontemporal_load((const f32x4*)(xc + base + co));
    sv1 = __builtin_nontemporal_load((const f32x4*)(xc + base + co + 4));
    ov0 = __builtin_nontemporal_load((const f32x4*)(other + base + co));
    ov1 = __builtin_nontemporal_load((const f32x4*)(other + base + co + 4));
  }
  f32x4 a0 = {}, a1 = {};
  if (!iso) {
    const int* csr = (const int*)csrv + (size_t)rel * N_EDGES;
    for (int e = e0; e < e1; e += 16) {
      int lim = e1 - 1;
      int src[4]; float wgt[4];
#pragma unroll
      for (int u = 0; u < 4; ++u) {
        int ee = e + 4 * u + g;
        src[u] = csr[min(ee, lim)];
        wgt[u] = (ee <= lim) ? 1.f : 0.f;
      }
      uint4 v[4];
#pragma unroll
      for (int u = 0; u < 4; ++u)
        v[u] = *(const uint4*)(mir + (size_t)src[u] * CH + co);
#pragma unroll
      for (int u = 0; u < 4; ++u) bf8_fma(v[u], wgt[u], a0, a1);
    }
  } else {
    const int2* csr = (const int2*)csrv + (size_t)rel * N_EDGES;
    for (int e = e0; e < e1; e += 16) {
      int lim = e1 - 1;
      int2 pm[4]; float wgt[4];
#pragma unroll
      for (int u = 0; u < 4; ++u) {
        int ee = e + 4 * u + g;
        pm[u] = csr[min(ee, lim)];
        wgt[u] = (ee <= lim) ? __int_as_float(pm[u].y) : 0.f;
      }
      uint4 v[4];
#pragma unroll
      for (int u = 0; u < 4; ++u)
        v[u] = *(const uint4*)(mir + (size_t)pm[u].x * CH + co);
#pragma unroll
      for (int u = 0; u < 4; ++u) bf8_fma(v[u], wgt[u], a0, a1);
    }
  }
#pragma unroll
  for (int m = 16; m < 64; m <<= 1) {
#pragma unroll
    for (int i = 0; i < 4; ++i) {
      a0[i] += __shfl_xor(a0[i], m);
      a1[i] += __shfl_xor(a1[i], m);
    }
  }
  if (g == 0) {
    float ws2 = iso ? wscale : ((e1 > e0) ? wscale / (float)(e1 - e0) : 0.f);
    f32x4 o0, o1;
#pragma unroll
    for (int i = 0; i < 4; ++i) {
      o0[i] = ws2 * a0[i] + aself * sv0[i] + beta * ov0[i];
      o1[i] = ws2 * a1[i] + aself * sv1[i] + beta * ov1[i];
    }
    *(f32x4*)(out + base + co) = o0;          // plain cached stores
    *(f32x4*)(out + base + co + 4) = o1;      // (nt stores => 4x write amp)
    uint4 m;
    m.x = (unsigned)f2bf(o0[0]) | ((unsigned)f2bf(o0[1]) << 16);
    m.y = (unsigned)f2bf(o0[2]) | ((unsigned)f2bf(o0[3]) << 16);
    m.z = (unsigned)f2bf(o1[0]) | ((unsigned)f2bf(o1[1]) << 16);
    m.w = (unsigned)f2bf(o1[2]) | ((unsigned)f2bf(o1[3]) << 16);
    *(uint4*)(omir + base + co) = m;
  }
}

// Round-8 fp32-gather body (fallback tiers + gprop).
__device__ __forceinline__ void prop_accum(
    const float* __restrict__ xc, const void* __restrict__ csrv, int r, int iso,
    int e0, int e1, int g, int l, float4& acc0, float4& acc1) {
  if (!iso) {
    const int* csr = (const int*)csrv + (size_t)r * N_EDGES;
    for (int e = e0; e < e1; e += 16) {
      int lim = e1 - 1;
      int src[4]; float wgt[4];
#pragma unroll
      for (int u = 0; u < 4; ++u) {
        int ee = e + 4 * u + g;
        src[u] = csr[min(ee, lim)];
        wgt[u] = (ee <= lim) ? 1.f : 0.f;
      }
      float4 va[4], vb[4];
#pragma unroll
      for (int u = 0; u < 4; ++u) {
        const float4* rs = (const float4*)(xc + (size_t)src[u] * CH);
        va[u] = rs[l];
        vb[u] = rs[l + 16];
      }
#pragma unroll
      for (int u = 0; u < 4; ++u) {
        float w0 = wgt[u];
        acc0.x = fmaf(w0, va[u].x, acc0.x); acc0.y = fmaf(w0, va[u].y, acc0.y);
        acc0.z = fmaf(w0, va[u].z, acc0.z); acc0.w = fmaf(w0, va[u].w, acc0.w);
        acc1.x = fmaf(w0, vb[u].x, acc1.x); acc1.y = fmaf(w0, vb[u].y, acc1.y);
        acc1.z = fmaf(w0, vb[u].z, acc1.z); acc1.w = fmaf(w0, vb[u].w, acc1.w);
      }
    }
  } else {
    const int2* csr = (const int2*)csrv + (size_t)r * N_EDGES;
    for (int e = e0; e < e1; e += 16) {
      int lim = e1 - 1;
      int2 pm[4]; float wgt[4];
#pragma unroll
      for (int u = 0; u < 4; ++u) {
        int ee = e + 4 * u + g;
        pm[u] = csr[min(ee, lim)];
        wgt[u] = (ee <= lim) ? __int_as_float(pm[u].y) : 0.f;
      }
      float4 va[4], vb[4];
#pragma unroll
      for (int u = 0; u < 4; ++u) {
        const float4* rs = (const float4*)(xc + (size_t)pm[u].x * CH);
        va[u] = rs[l];
        vb[u] = rs[l + 16];
      }
#pragma unroll
      for (int u = 0; u < 4; ++u) {
        float w0 = wgt[u];
        acc0.x = fmaf(w0, va[u].x, acc0.x); acc0.y = fmaf(w0, va[u].y, acc0.y);
        acc0.z = fmaf(w0, va[u].z, acc0.z); acc0.w = fmaf(w0, va[u].w, acc0.w);
        acc1.x = fmaf(w0, vb[u].x, acc1.x); acc1.y = fmaf(w0, vb[u].y, acc1.y);
        acc1.z = fmaf(w0, vb[u].z, acc1.z); acc1.w = fmaf(w0, vb[u].w, acc1.w);
      }
    }
  }
}

__global__ __launch_bounds__(256, 8) void k_prop(
    const float* __restrict__ xcb, const float* __restrict__ otherb,
    float* __restrict__ outb, const int* __restrict__ off3,
    const void* __restrict__ csrv, const int* __restrict__ flag, int rel0,
    size_t slab, float wscale, float aself, float beta) {
  int node = blockIdx.x * 4 + (threadIdx.x >> 6);
  if (node >= N_NODES) return;
  int rel = rel0 + blockIdx.y;
  const float* xc = xcb + (size_t)blockIdx.y * slab;
  const float* other = otherb + (size_t)blockIdx.y * slab;
  float* out = outb + (size_t)blockIdx.y * slab;
  const int* off = off3 + rel * (N_NODES + 1);
  int iso = flag[1];
  int lane = threadIdx.x & 63;
  int g = lane >> 4, l = lane & 15;
  int e0 = off[node], e1 = off[node + 1];
  size_t base = (size_t)node * CH;
  int go = (g & 1) * 64;
  float4 sv = *(const float4*)(xc + base + go + 4 * l);
  float4 ov = *(const float4*)(other + base + go + 4 * l);
  float4 acc0 = make_float4(0.f, 0.f, 0.f, 0.f);
  float4 acc1 = make_float4(0.f, 0.f, 0.f, 0.f);
  prop_accum(xc, csrv, rel, iso, e0, e1, g, l, acc0, acc1);
#pragma unroll
  for (int m = 16; m < 64; m <<= 1) {
    acc0.x += __shfl_xor(acc0.x, m); acc0.y += __shfl_xor(acc0.y, m);
    acc0.z += __shfl_xor(acc0.z, m); acc0.w += __shfl_xor(acc0.w, m);
    acc1.x += __shfl_xor(acc1.x, m); acc1.y += __shfl_xor(acc1.y, m);
    acc1.z += __shfl_xor(acc1.z, m); acc1.w += __shfl_xor(acc1.w, m);
  }
  float ws2 = iso ? wscale : ((e1 > e0) ? wscale / (float)(e1 - e0) : 0.f);
  if (g == 0) {
    float4 o;
    o.x = ws2 * acc0.x + aself * sv.x + beta * ov.x;
    o.y = ws2 * acc0.y + aself * sv.y + beta * ov.y;
    o.z = ws2 * acc0.z + aself * sv.z + beta * ov.z;
    o.w = ws2 * acc0.w + aself * sv.w + beta * ov.w;
    *(float4*)(out + base + 4 * l) = o;
  } else if (g == 1) {
    float4 o;
    o.x = ws2 * acc1.x + aself * sv.x + beta * ov.x;
    o.y = ws2 * acc1.y + aself * sv.y + beta * ov.y;
    o.z = ws2 * acc1.z + aself * sv.z + beta * ov.z;
    o.w = ws2 * acc1.w + aself * sv.w + beta * ov.w;
    *(float4*)(out + base + 64 + 4 * l) = o;
  }
}

// Fused final step + batch gather (+ sqrt(deg) rescale on fast path).
__global__ __launch_bounds__(256) void k_gprop(
    const float* __restrict__ y3b, const float* __restrict__ y2b,
    const int* __restrict__ off3, const void* __restrict__ csrv,
    const int* __restrict__ flag, const int* __restrict__ batch,
    float* __restrict__ out, int rel0, size_t slab,
    float wscale, float aself, float beta) {
  int b = blockIdx.x * 4 + (threadIdx.x >> 6);
  if (b >= BATCH) return;
  int rel = rel0 + blockIdx.y;
  const float* y3 = y3b + (size_t)blockIdx.y * slab;
  const float* y2 = y2b + (size_t)blockIdx.y * slab;
  const int* off = off3 + rel * (N_NODES + 1);
  int i64 = flag[0], iso = flag[1];
  int node = i64 ? batch[2 * b] : batch[b];
  int lane = threadIdx.x & 63;
  int g = lane >> 4, l = lane & 15;
  int e0 = off[node], e1 = off[node + 1];
  size_t base = (size_t)node * CH;
  int go = (g & 1) * 64;
  float4 sv = *(const float4*)(y3 + base + go + 4 * l);
  float4 ov = *(const float4*)(y2 + base + go + 4 * l);
  float4 acc0 = make_float4(0.f, 0.f, 0.f, 0.f);
  float4 acc1 = make_float4(0.f, 0.f, 0.f, 0.f);
  prop_accum(y3, csrv, rel, iso, e0, e1, g, l, acc0, acc1);
#pragma unroll
  for (int m = 16; m < 64; m <<= 1) {
    acc0.x += __shfl_xor(acc0.x, m); acc0.y += __shfl_xor(acc0.y, m);
    acc0.z += __shfl_xor(acc0.z, m); acc0.w += __shfl_xor(acc0.w, m);
    acc1.x += __shfl_xor(acc1.x, m); acc1.y += __shfl_xor(acc1.y, m);
    acc1.z += __shfl_xor(acc1.z, m); acc1.w += __shfl_xor(acc1.w, m);
  }
  int deg = e1 - e0;
  float ws2 = iso ? wscale : ((deg > 0) ? wscale / (float)deg : 0.f);
  float osc = iso ? 1.0f : sqrtf((float)deg);
  float* orow = out + (size_t)b * (N_REL * CH) + rel * CH;
  if (g == 0) {
    float4 o;
    o.x = osc * (ws2 * acc0.x + aself * sv.x + beta * ov.x);
    o.y = osc * (ws2 * acc0.y + aself * sv.y + beta * ov.y);
    o.z = osc * (ws2 * acc0.z + aself * sv.z + beta * ov.z);
    o.w = osc * (ws2 * acc0.w + aself * sv.w + beta * ov.w);
    *(float4*)(orow + 4 * l) = o;
  } else if (g == 1) {
    float4 o;
    o.x = osc * (ws2 * acc1.x + aself * sv.x + beta * ov.x);
    o.y = osc * (ws2 * acc1.y + aself * sv.y + beta * ov.y);
    o.z = osc * (ws2 * acc1.z + aself * sv.z + beta * ov.z);
    o.w = osc * (ws2 * acc1.w + aself * sv.w + beta * ov.w);
    *(float4*)(orow + 64 + 4 * l) = o;
  }
}

extern "C" void kernel_launch(void* const* d_in, const int* in_sizes, int n_in,
                              void* d_out, int out_size, void* d_ws, size_t ws_size,
                              hipStream_t stream) {
  const float* features   = (const float*)d_in[0];
  const int*   edge_index = (const int*)d_in[1];
  const int*   batch_nodes= (const int*)d_in[2];
  const float* lin0_w     = (const float*)d_in[3];
  const float* lin0_b     = (const float*)d_in[4];
  const float* lin1_w     = (const float*)d_in[5];
  const float* lin1_b     = (const float*)d_in[6];
  float* out = (float*)d_out;

  const size_t slabElems = (size_t)N_NODES * CH;

  char* w = (char*)d_ws;
  size_t o = 0;
  auto nxt = [&](size_t bytes) {
    char* p = w + o;
    o = (o + bytes + 255) & ~(size_t)255;
    return p;
  };
  int*   flag  = (int*)  nxt(256);
  int*   deg3  = (int*)  nxt((size_t)3 * N_NODES * 4);
  int*   cur3  = (int*)  nxt((size_t)3 * N_NODES * 4);
  float* dinv3 = (float*)nxt((size_t)3 * N_NODES * 4);
  int*   off3  = (int*)  nxt((size_t)3 * (N_NODES + 1) * 4);
  void*  csr   = (void*) nxt((size_t)3 * N_EDGES * 8);
  size_t avail = (ws_size > o) ? ws_size - o : 0;
  const bool fused = avail >= 2 * 3 * slabElems * 4 + 4096;
  const bool mirOk = avail >= 2 * 3 * slabElems * 4 + 2 * 3 * slabElems * 2 + 8192;
  const int nslab = fused ? 3 : 1;
  float*  A    = (float*) nxt((size_t)nslab * slabElems * 4);
  float*  B    = (float*) nxt((size_t)nslab * slabElems * 4);
  ushort* Amir = mirOk ? (ushort*)nxt((size_t)3 * slabElems * 2) : nullptr;
  ushort* Bmir = mirOk ? (ushort*)nxt((size_t)3 * slabElems * 2) : nullptr;

  hipMemsetAsync(flag, 0, 8, stream);
  hipMemsetAsync(deg3, 0, (size_t)3 * N_NODES * 4, stream);
  hipMemsetAsync(cur3, 0, (size_t)3 * N_NODES * 4, stream);
  k_detect<<<1, 64, 0, stream>>>(edge_index, flag);
  const int NCHUNK = (N_EDGES + 255) / 256;   // 3125
  k_hist3x<<<dim3(NCHUNK * NRANGE, 3), 256, 0, stream>>>(edge_index, flag, deg3);
  k_dinv3<<<(3 * N_NODES + 255) / 256, 256, 0, stream>>>(deg3, dinv3, flag);
  k_scan3<<<3, 1024, 0, stream>>>(deg3, off3);
  k_fill3x<<<dim3(NCHUNK * NRANGE, 3), 256, 0, stream>>>(edge_index, flag, off3,
                                                         cur3, dinv3, csr);

  const float h2 = DT * DT;
  if (fused) {
    for (int r = 0; r < N_REL; ++r) {
      k_phi_mfma<<<dim3((N_NODES + 127) / 128, 2), 256, 0, stream>>>(
          features, lin0_w + (size_t)r * CH * F_IN, lin0_b + (size_t)r * CH,
          lin1_w + (size_t)r * CH * F_IN, lin1_b + (size_t)r * CH,
          dinv3 + r * N_NODES, flag, A + (size_t)r * slabElems,
          B + (size_t)r * slabElems);
    }
    const long n8 = (long)3 * slabElems / 8;
    if (mirOk) {
      k_mir<<<(int)((n8 + 255) / 256), 256, 0, stream>>>(A, Amir, n8);
      // Y1 = dt*q1 + 0.5h^2*Sum(q0) + q0   : gather Amir -> B, Bmir
      k_prop_m<<<dim3((N_NODES + 3) / 4, 3), 256, 0, stream>>>(
          A, Amir, B, B, Bmir, off3, csr, flag, slabElems, 0.5f * h2, 1.0f, DT);
      // Y2 = h^2*Sum(Y1) + 2*Y1 - q0       : gather Bmir -> A, Amir
      k_prop_m<<<dim3((N_NODES + 3) / 4, 3), 256, 0, stream>>>(
          B, Bmir, A, A, Amir, off3, csr, flag, slabElems, h2, 2.0f, -1.0f);
      // Y3 = h^2*Sum(Y2) + 2*Y2 - Y1       : gather Amir -> B, Bmir
      k_prop_m<<<dim3((N_NODES + 3) / 4, 3), 256, 0, stream>>>(
          A, Amir, B, B, Bmir, off3, csr, flag, slabElems, h2, 2.0f, -1.0f);
    } else {
      k_prop<<<dim3((N_NODES + 3) / 4, 3), 256, 0, stream>>>(
          A, B, B, off3, csr, flag, 0, slabElems, 0.5f * h2, 1.0f, DT);
      k_prop<<<dim3((N_NODES + 3) / 4, 3), 256, 0, stream>>>(
          B, A, A, off3, csr, flag, 0, slabElems, h2, 2.0f, -1.0f);
      k_prop<<<dim3((N_NODES + 3) / 4, 3), 256, 0, stream>>>(
          A, B, B, off3, csr, flag, 0, slabElems, h2, 2.0f, -1.0f);
    }
    // Y4[batch] fused with gather -> out (fp32 gather of Y3 = B)
    k_gprop<<<dim3((BATCH + 3) / 4, 3), 256, 0, stream>>>(
        B, A, off3, csr, flag, batch_nodes, out, 0, slabElems, h2, 2.0f, -1.0f);
  } else {
    for (int r = 0; r < N_REL; ++r) {
      k_phi_mfma<<<dim3((N_NODES + 127) / 128, 2), 256, 0, stream>>>(
          features, lin0_w + (size_t)r * CH * F_IN, lin0_b + (size_t)r * CH,
          lin1_w + (size_t)r * CH * F_IN, lin1_b + (size_t)r * CH,
          dinv3 + r * N_NODES, flag, A, B);
      k_prop<<<dim3((N_NODES + 3) / 4, 1), 256, 0, stream>>>(
          A, B, B, off3, csr, flag, r, 0, 0.5f * h2, 1.0f, DT);
      k_prop<<<dim3((N_NODES + 3) / 4, 1), 256, 0, stream>>>(
          B, A, A, off3, csr, flag, r, 0, h2, 2.0f, -1.0f);
      k_prop<<<dim3((N_NODES + 3) / 4, 1), 256, 0, stream>>>(
          A, B, B, off3, csr, flag, r, 0, h2, 2.0f, -1.0f);
      k_gprop<<<dim3((BATCH + 3) / 4, 1), 256, 0, stream>>>(
          B, A, off3, csr, flag, batch_nodes, out, r, 0, h2, 2.0f, -1.0f);
    }
  }
}